// Round 5
// baseline (7946.794 us; speedup 1.0000x reference)
//
#include <hip/hip_runtime.h>
#include <hip/hip_cooperative_groups.h>
#include <math.h>

namespace cg = cooperative_groups;

// Problem constants
constexpr int NB = 128;    // batch
constexpr int NH = 512;    // hidden
constexpr int NE = 256;    // embed
constexpr int NV = 32000;  // vocab
constexpr int NT = 32;     // steps
constexpr int NVBW = 1000; // 250 v-blocks * 4 wave-columns (32 vocab each)

typedef _Float16 half8 __attribute__((ext_vector_type(8)));
typedef float    f32x4 __attribute__((ext_vector_type(4)));

// ---------------------------------------------------------------------------
// One cooperative mega-kernel: grid = 256 blocks x 512 threads (1 block/CU).
// P0: zero output + f32->f16 weight conversion.
// Per step: logits phase (250 blocks, f16 MFMA, 128 vocab each) -> grid.sync
//           emit+RNN phase (128 blocks, one batch row each)     -> grid.sync
// ---------------------------------------------------------------------------
__global__ __launch_bounds__(512, 2)
void speaker_kernel(const float* __restrict__ z,    const float* __restrict__ Wemb,
                    const float* __restrict__ bemb, const float* __restrict__ Wih,
                    const float* __restrict__ bih,  const float* __restrict__ Whh,
                    const float* __restrict__ bhh,  const float* __restrict__ Wlin,
                    const float* __restrict__ blin, float* __restrict__ out,
                    _Float16* __restrict__ Wh, _Float16* __restrict__ hidh,
                    _Float16* __restrict__ zh, float* __restrict__ hid,
                    float* __restrict__ pm1, int* __restrict__ pi1,
                    float* __restrict__ pm2, int* __restrict__ pi2,
                    float* __restrict__ ps,  float* __restrict__ lps,
                    float* __restrict__ maskp)
{
    cg::grid_group grid = cg::this_grid();

    __shared__ _Float16 sm[2][2][128][64];   // 64 KiB (logits staging)
    __shared__ float red8[8];
    __shared__ int   cand[32];
    __shared__ float cval[32];
    __shared__ int   ncand;
    __shared__ int   besti;
    __shared__ float es[NE];
    __shared__ float hs[NH];

    const int blk  = blockIdx.x;
    const int tid  = threadIdx.x;
    const int gtid = blk * 512 + tid;
    constexpr int GT = 256 * 512;

    // ---- P0: zero d_out; convert Wlin->Wh, z->zh -----------------------
    {
        const float4 z4 = {0.f, 0.f, 0.f, 0.f};
        float4* o4 = (float4*)out;
        for (int i = gtid; i < (NT * NB * NV + NB) / 4; i += GT) o4[i] = z4;
        for (int i = gtid; i < NV * NH / 8; i += GT) {
            float4 a = ((const float4*)Wlin)[i * 2];
            float4 b = ((const float4*)Wlin)[i * 2 + 1];
            half8 h = { (_Float16)a.x, (_Float16)a.y, (_Float16)a.z, (_Float16)a.w,
                        (_Float16)b.x, (_Float16)b.y, (_Float16)b.z, (_Float16)b.w };
            ((half8*)Wh)[i] = h;
        }
        for (int i = gtid; i < NB * NH / 8; i += GT) {
            float4 a = ((const float4*)z)[i * 2];
            float4 b = ((const float4*)z)[i * 2 + 1];
            half8 h = { (_Float16)a.x, (_Float16)a.y, (_Float16)a.z, (_Float16)a.w,
                        (_Float16)b.x, (_Float16)b.y, (_Float16)b.z, (_Float16)b.w };
            ((half8*)zh)[i] = h;
        }
    }
    __threadfence();
    grid.sync();

    const int w    = tid >> 6;
    const int lane = tid & 63;

    for (int t = 0; t < NT; t++) {
        // ================= logits phase (blocks 0..249) =================
        if (blk < 250) {
            const _Float16* Ah = (t == 0) ? zh : hidh;
            const int wm = w >> 2;
            const int wn = w & 3;
            const int vb = blk;
            const int v0 = vb * 128;

            const _Float16* gp[4];
            unsigned ldsoff[4];
#pragma unroll
            for (int c = 0; c < 4; c++) {
                int slot = w * 256 + c * 64 + lane;
                int mat  = slot >> 10;
                int r    = (slot >> 3) & 127;
                int sp   = slot & 7;
                int s    = sp ^ (r & 7);
                const _Float16* base = mat ? (Wh + (size_t)(v0 + r) * NH)
                                           : (Ah + (size_t)r * NH);
                gp[c] = base + s * 8;
                ldsoff[c] = (unsigned)(w * 256 + c * 64) * 16;  // wave-uniform
            }

#define STAGE(db, k0)                                                          \
    do {                                                                       \
        _Pragma("unroll")                                                      \
        for (int c = 0; c < 4; c++) {                                          \
            __builtin_amdgcn_global_load_lds(                                  \
                (const __attribute__((address_space(1))) unsigned*)(gp[c] + (k0)), \
                (__attribute__((address_space(3))) unsigned*)((char*)&sm[db][0][0][0] + ldsoff[c]), \
                16, 0, 0);                                                     \
        }                                                                      \
    } while (0)

            f32x4 acc[4][2];
#pragma unroll
            for (int mi = 0; mi < 4; mi++)
#pragma unroll
                for (int ni = 0; ni < 2; ni++) acc[mi][ni] = {0.f, 0.f, 0.f, 0.f};

            STAGE(0, 0);
            asm volatile("s_waitcnt vmcnt(0)" ::: "memory");
            __builtin_amdgcn_sched_barrier(0);
            __builtin_amdgcn_s_barrier();

            int db = 0;
            for (int kt = 0; kt < 8; kt++) {
                if (kt < 7) STAGE(db ^ 1, (kt + 1) * 64);
#pragma unroll
                for (int kk = 0; kk < 2; kk++) {
                    const int sbase = kk * 4 + (lane >> 4);
                    half8 af[4], bf[2];
#pragma unroll
                    for (int mi = 0; mi < 4; mi++) {
                        int r = wm * 64 + mi * 16 + (lane & 15);
                        af[mi] = *(const half8*)&sm[db][0][r][(sbase ^ (r & 7)) * 8];
                    }
#pragma unroll
                    for (int ni = 0; ni < 2; ni++) {
                        int rb = wn * 32 + ni * 16 + (lane & 15);
                        bf[ni] = *(const half8*)&sm[db][1][rb][(sbase ^ (rb & 7)) * 8];
                    }
#pragma unroll
                    for (int mi = 0; mi < 4; mi++)
#pragma unroll
                        for (int ni = 0; ni < 2; ni++)
                            acc[mi][ni] = __builtin_amdgcn_mfma_f32_16x16x32_f16(
                                af[mi], bf[ni], acc[mi][ni], 0, 0, 0);
                }
                asm volatile("s_waitcnt vmcnt(0)" ::: "memory");
                __builtin_amdgcn_sched_barrier(0);
                __builtin_amdgcn_s_barrier();
                db ^= 1;
            }
#undef STAGE

            // epilogue: per-row top-2 + sumexp over this wave's 32 columns
            const int colbase = v0 + wn * 32 + (lane & 15);
            const float bias0 = blin[colbase];
            const float bias1 = blin[colbase + 16];
            const int cidx = vb * 4 + wn;

#pragma unroll
            for (int mi = 0; mi < 4; mi++) {
#pragma unroll
                for (int reg = 0; reg < 4; reg++) {
                    const int b = wm * 64 + mi * 16 + (lane >> 4) * 4 + reg;
                    const float va = acc[mi][0][reg] + bias0;
                    const float vc = acc[mi][1][reg] + bias1;
                    float a1, a2; int j1, j2;
                    if (va >= vc) { a1 = va; j1 = colbase;      a2 = vc; j2 = colbase + 16; }
                    else          { a1 = vc; j1 = colbase + 16; a2 = va; j2 = colbase; }
#pragma unroll
                    for (int off = 1; off < 16; off <<= 1) {
                        float o1 = __shfl_xor(a1, off), o2 = __shfl_xor(a2, off);
                        int   k1 = __shfl_xor(j1, off), k2 = __shfl_xor(j2, off);
                        float n1, n2; int m1, m2;
                        bool ob = (o1 > a1) || (o1 == a1 && k1 < j1);
                        if (ob) {
                            n1 = o1; m1 = k1;
                            bool t2 = (a1 > o2) || (a1 == o2 && j1 < k2);
                            if (t2) { n2 = a1; m2 = j1; } else { n2 = o2; m2 = k2; }
                        } else {
                            n1 = a1; m1 = j1;
                            bool t2 = (o1 > a2) || (o1 == a2 && k1 < j2);
                            if (t2) { n2 = o1; m2 = k1; } else { n2 = a2; m2 = j2; }
                        }
                        a1 = n1; j1 = m1; a2 = n2; j2 = m2;
                    }
                    float s = __expf(va - a1) + __expf(vc - a1);
#pragma unroll
                    for (int off = 1; off < 16; off <<= 1) s += __shfl_xor(s, off);
                    if ((lane & 15) == 0) {
                        pm1[b * NVBW + cidx] = a1;  pi1[b * NVBW + cidx] = j1;
                        pm2[b * NVBW + cidx] = a2;  pi2[b * NVBW + cidx] = j2;
                        ps [b * NVBW + cidx] = s;
                    }
                }
            }
        }
        __threadfence();
        grid.sync();

        // ================= emit + RNN phase (blocks 0..127) =============
        if (blk < NB) {
            constexpr float DELTA = 0.01f;
            constexpr int   MAXC  = 32;
            const int b = blk;
            const float* hid_in = (t == 0) ? z : hid;

            hs[tid] = hid_in[(size_t)b * NH + tid];   // 512 threads cover NH
            if (tid == 0) ncand = 0;
            __syncthreads();

            // phase 1: global max of pm1 (8-wave reduction)
            float m_ = -1e30f;
            for (int c = tid; c < NVBW; c += 512) m_ = fmaxf(m_, pm1[b * NVBW + c]);
#pragma unroll
            for (int off = 1; off < 64; off <<= 1) m_ = fmaxf(m_, __shfl_xor(m_, off));
            if (lane == 0) red8[w] = m_;
            __syncthreads();
            const float gmax = fmaxf(fmaxf(fmaxf(red8[0], red8[1]), fmaxf(red8[2], red8[3])),
                                     fmaxf(fmaxf(red8[4], red8[5]), fmaxf(red8[6], red8[7])));
            __syncthreads();

            // phase 2: softmax denominator + candidate collection
            float s = 0.f;
            for (int c = tid; c < NVBW; c += 512) {
                float p1 = pm1[b * NVBW + c];
                s += ps[b * NVBW + c] * __expf(p1 - gmax);
                if (p1 >= gmax - DELTA) {
                    int pos = atomicAdd(&ncand, 1);
                    if (pos < MAXC) cand[pos] = pi1[b * NVBW + c];
                }
                float p2 = pm2[b * NVBW + c];
                if (p2 >= gmax - DELTA) {
                    int pos = atomicAdd(&ncand, 1);
                    if (pos < MAXC) cand[pos] = pi2[b * NVBW + c];
                }
            }
#pragma unroll
            for (int off = 1; off < 64; off <<= 1) s += __shfl_xor(s, off);
            if (lane == 0) red8[w] = s;
            __syncthreads();
            const float tot = ((red8[0] + red8[1]) + (red8[2] + red8[3]))
                            + ((red8[4] + red8[5]) + (red8[6] + red8[7]));
            const int nc = min(ncand, MAXC);

            // phase 3: exact fp32 rescore of candidates (one wave each)
            for (int ci = w; ci < nc; ci += 8) {
                int tok = cand[ci];
                float4 h0 = ((const float4*)hs)[lane * 2];
                float4 h1 = ((const float4*)hs)[lane * 2 + 1];
                const float4* wv = (const float4*)(Wlin + (size_t)tok * NH);
                float4 w0 = wv[lane * 2], w1 = wv[lane * 2 + 1];
                float d = h0.x * w0.x + h0.y * w0.y + h0.z * w0.z + h0.w * w0.w
                        + h1.x * w1.x + h1.y * w1.y + h1.z * w1.z + h1.w * w1.w;
#pragma unroll
                for (int off = 1; off < 64; off <<= 1) d += __shfl_xor(d, off);
                if (lane == 0) cval[ci] = d + blin[tok];
            }
            __syncthreads();

            // phase 4: argmax among candidates; state update; one-hot write
            if (tid == 0) {
                float bv = cval[0]; int bi = cand[0];
                for (int ci = 1; ci < nc; ci++)
                    if (cval[ci] > bv || (cval[ci] == bv && cand[ci] < bi)) { bv = cval[ci]; bi = cand[ci]; }
                float lp = (bv - gmax) - logf(tot);
                float lpv, mk;
                if (t == 0) { lpv = lp; mk = (bi == 0) ? 0.f : 1.f; }
                else {
                    lpv = lps[b]; mk = maskp[b];
                    lpv += mk * lp;
                    mk *= (bi == 0) ? 0.f : 1.f;
                }
                lps[b] = lpv; maskp[b] = mk;
                out[(size_t)t * NB * NV + (size_t)b * NV + bi] = 1.0f;
                if (t == NT - 1) out[(size_t)NT * NB * NV + b] = lpv;
                besti = bi;
            }
            __syncthreads();
            const int gi = besti;

            if (t < NT - 1) {
                // phase 5: embedding gather (first 256 threads)
                if (tid < NE) es[tid] = Wemb[(size_t)tid * NV + gi] + bemb[tid];
                __syncthreads();

                // phase 6: Elman cell (512 threads, 1 h each)
                const int h = tid;
                float acc = bih[h] + bhh[h];
                const float4* wi = (const float4*)(Wih + (size_t)h * NE);
#pragma unroll 4
                for (int e4 = 0; e4 < NE / 4; e4++) {
                    float4 ww = wi[e4];
                    acc += ww.x * es[e4 * 4] + ww.y * es[e4 * 4 + 1]
                         + ww.z * es[e4 * 4 + 2] + ww.w * es[e4 * 4 + 3];
                }
                const float4* wh = (const float4*)(Whh + (size_t)h * NH);
#pragma unroll 4
                for (int k4 = 0; k4 < NH / 4; k4++) {
                    float4 ww = wh[k4];
                    acc += ww.x * hs[k4 * 4] + ww.y * hs[k4 * 4 + 1]
                         + ww.z * hs[k4 * 4 + 2] + ww.w * hs[k4 * 4 + 3];
                }
                float v = tanhf(acc);
                hid[(size_t)b * NH + h]  = v;
                hidh[(size_t)b * NH + h] = (_Float16)v;
            }
        }
        __threadfence();
        grid.sync();
    }
}

// ---------------------------------------------------------------------------
extern "C" void kernel_launch(void* const* d_in, const int* in_sizes, int n_in,
                              void* d_out, int out_size, void* d_ws, size_t ws_size,
                              hipStream_t stream) {
    const float* z    = (const float*)d_in[0];
    const float* Wemb = (const float*)d_in[1];
    const float* bemb = (const float*)d_in[2];
    const float* Wih  = (const float*)d_in[3];
    const float* bih  = (const float*)d_in[4];
    const float* Whh  = (const float*)d_in[5];
    const float* bhh  = (const float*)d_in[6];
    const float* Wlin = (const float*)d_in[7];
    const float* blin = (const float*)d_in[8];
    float* out = (float*)d_out;

    char* ws = (char*)d_ws;
    _Float16* Wh    = (_Float16*)(ws);                 // 32,768,000 B
    _Float16* hidh  = (_Float16*)(ws + 32768000);      // 131,072 B
    _Float16* zh    = (_Float16*)(ws + 32899072);      // 131,072 B
    float*    hid   = (float*)   (ws + 33030144);      // 262,144 B
    float*    pm1   = (float*)   (ws + 33292288);      // 512,000 B
    int*      pi1   = (int*)     (ws + 33804288);
    float*    pm2   = (float*)   (ws + 34316288);
    int*      pi2   = (int*)     (ws + 34828288);
    float*    ps    = (float*)   (ws + 35340288);
    float*    lps   = (float*)   (ws + 35852288);
    float*    maskp = (float*)   (ws + 35852800);

    void* args[] = {
        (void*)&z, (void*)&Wemb, (void*)&bemb, (void*)&Wih, (void*)&bih,
        (void*)&Whh, (void*)&bhh, (void*)&Wlin, (void*)&blin, (void*)&out,
        (void*)&Wh, (void*)&hidh, (void*)&zh, (void*)&hid,
        (void*)&pm1, (void*)&pi1, (void*)&pm2, (void*)&pi2, (void*)&ps,
        (void*)&lps, (void*)&maskp
    };
    hipLaunchCooperativeKernel((void*)speaker_kernel, dim3(256), dim3(512),
                               args, 0, stream);
}

// Round 6
// 3605.451 us; speedup vs baseline: 2.2041x; 2.2041x over previous
//
#include <hip/hip_runtime.h>
#include <math.h>

// Problem constants
constexpr int NB = 128;    // batch
constexpr int NH = 512;    // hidden
constexpr int NE = 256;    // embed
constexpr int NV = 32000;  // vocab
constexpr int NT = 32;     // steps
constexpr int NVBW = 1000; // 250 v-blocks * 4 wave-columns (32 vocab each)

typedef _Float16 half8 __attribute__((ext_vector_type(8)));
typedef float    f32x4 __attribute__((ext_vector_type(4)));

#define AGLD(p)    __hip_atomic_load((p), __ATOMIC_RELAXED, __HIP_MEMORY_SCOPE_AGENT)
#define AGST(p, v) __hip_atomic_store((p), (v), __ATOMIC_RELAXED, __HIP_MEMORY_SCOPE_AGENT)

// Zero the barrier counter before the cooperative kernel (ws is poisoned 0xAA
// before every timed replay; kernel-boundary flush makes this visible).
__global__ void init_kernel(unsigned* cnt) { *cnt = 0u; }

// Fence-free grid barrier: monotonic device-scope counter. All communicated
// data uses uncached (agent-scope) loads/stores, so NO cache maintenance is
// needed -- only per-wave vmcnt drain before arrival.
__device__ __forceinline__ void gsync(unsigned* cnt, unsigned target) {
    asm volatile("s_waitcnt vmcnt(0) lgkmcnt(0)" ::: "memory");
    __syncthreads();
    if (threadIdx.x == 0) {
        __hip_atomic_fetch_add(cnt, 1u, __ATOMIC_RELAXED, __HIP_MEMORY_SCOPE_AGENT);
        while (AGLD(cnt) < target) __builtin_amdgcn_s_sleep(4);
    }
    __syncthreads();
    asm volatile("" ::: "memory");
}

// ---------------------------------------------------------------------------
// Cooperative mega-kernel: 256 blocks x 512 threads (1/CU, persistent).
// ---------------------------------------------------------------------------
__global__ __launch_bounds__(512, 2)
void speaker_kernel(const float* __restrict__ z,    const float* __restrict__ Wemb,
                    const float* __restrict__ bemb, const float* __restrict__ Wih,
                    const float* __restrict__ bih,  const float* __restrict__ Whh,
                    const float* __restrict__ bhh,  const float* __restrict__ Wlin,
                    const float* __restrict__ blin, float* __restrict__ out,
                    _Float16* __restrict__ Wh,      unsigned long long* __restrict__ hidh64,
                    float* __restrict__ hid,
                    float* __restrict__ pm1, int* __restrict__ pi1,
                    float* __restrict__ pm2, int* __restrict__ pi2,
                    float* __restrict__ ps,  float* __restrict__ lps,
                    float* __restrict__ maskp, unsigned* __restrict__ cnt)
{
    __shared__ _Float16 smA[128][64];        // 16 KiB, XOR-swizzled slots
    __shared__ _Float16 smB[2][128][64];     // 32 KiB dbuf, XOR-swizzled
    __shared__ float red8[8];
    __shared__ int   cand[32];
    __shared__ float cval[32];
    __shared__ int   ncand;
    __shared__ int   besti;
    __shared__ float es[NE];
    __shared__ float hs[NH];
    __shared__ _Float16 hsout[NH];

    const int blk  = blockIdx.x;
    const int tid  = threadIdx.x;
    const int w    = tid >> 6;
    const int lane = tid & 63;
    const int gtid = blk * 512 + tid;
    constexpr int GT = 256 * 512;
    unsigned sno = 0;

    unsigned long long* Wh64 = (unsigned long long*)Wh;

    // ---- P0: Wh = f16(Wlin) (uncached); hidh = f16(z) (uncached) --------
    for (int i = gtid; i < NV * NH / 4; i += GT) {
        float4 a = ((const float4*)Wlin)[i];
        union { _Float16 h[4]; unsigned long long u; } p;
        p.h[0] = (_Float16)a.x; p.h[1] = (_Float16)a.y;
        p.h[2] = (_Float16)a.z; p.h[3] = (_Float16)a.w;
        AGST(Wh64 + i, p.u);
    }
    for (int i = gtid; i < NB * NH / 4; i += GT) {
        float4 a = ((const float4*)z)[i];
        union { _Float16 h[4]; unsigned long long u; } p;
        p.h[0] = (_Float16)a.x; p.h[1] = (_Float16)a.y;
        p.h[2] = (_Float16)a.z; p.h[3] = (_Float16)a.w;
        AGST(hidh64 + i, p.u);
    }
    ++sno; gsync(cnt, sno * 256u);

    for (int t = 0; t < NT; t++) {
        // ================= logits phase (blocks 0..249) =================
        if (blk < 250) {
            const int wm = w >> 2;
            const int wn = w & 3;
            const int v0 = blk * 128;

            // B staging (global_load_lds, cached Wh): 1024 slots, 2/lane/wave
            const _Float16* gpB[2];
            unsigned ldsoffB[2];
#pragma unroll
            for (int c = 0; c < 2; c++) {
                int slot = w * 128 + c * 64 + lane;
                int r    = slot >> 3;
                int sp   = slot & 7;
                int g    = sp ^ (r & 7);
                gpB[c] = Wh + (size_t)(v0 + r) * NH + g * 8;
                ldsoffB[c] = (unsigned)(w * 128 + c * 64) * 16;  // wave-uniform
            }
#define STAGE_B(dbuf, k0)                                                      \
    do {                                                                       \
        _Pragma("unroll")                                                      \
        for (int c = 0; c < 2; c++) {                                          \
            __builtin_amdgcn_global_load_lds(                                  \
                (const __attribute__((address_space(1))) unsigned*)(gpB[c] + (k0)), \
                (__attribute__((address_space(3))) unsigned*)((char*)&smB[0][0][0] + (dbuf)*16384 + ldsoffB[c]), \
                16, 0, 0);                                                     \
        }                                                                      \
    } while (0)

            // A loader: uncached hidh -> regs -> ds_write (swizzled layout)
            const int ar   = tid >> 2;            // row 0..127
            const int asp0 = (tid & 3) * 2;       // lds slot pair
            const int ag0  = asp0 ^ (ar & 7);
            const int ag1  = (asp0 + 1) ^ (ar & 7);
            const unsigned long long* hbase = hidh64 + ar * 128;

            f32x4 acc[4][2];
#pragma unroll
            for (int mi = 0; mi < 4; mi++)
#pragma unroll
                for (int ni = 0; ni < 2; ni++) acc[mi][ni] = {0.f, 0.f, 0.f, 0.f};

            unsigned long long a0, a1, a2, a3;
            a0 = AGLD(hbase + ag0 * 2);     a1 = AGLD(hbase + ag0 * 2 + 1);
            a2 = AGLD(hbase + ag1 * 2);     a3 = AGLD(hbase + ag1 * 2 + 1);
            STAGE_B(0, 0);

#pragma unroll
            for (int kt = 0; kt < 8; kt++) {
                // write A tile kt (safe: all waves past previous end-barrier)
                {
                    unsigned long long* dA = (unsigned long long*)&smA[ar][asp0 * 8];
                    dA[0] = a0; dA[1] = a1; dA[2] = a2; dA[3] = a3;
                }
                if (kt < 7) {
                    const unsigned long long* hb = hbase + (kt + 1) * 16;
                    a0 = AGLD(hb + ag0 * 2); a1 = AGLD(hb + ag0 * 2 + 1);
                    a2 = AGLD(hb + ag1 * 2); a3 = AGLD(hb + ag1 * 2 + 1);
                    STAGE_B((kt + 1) & 1, (kt + 1) * 64);
                }
                __builtin_amdgcn_sched_barrier(0);
                if (kt < 7) asm volatile("s_waitcnt vmcnt(6)" ::: "memory");
                else        asm volatile("s_waitcnt vmcnt(0)" ::: "memory");
                __builtin_amdgcn_sched_barrier(0);
                __syncthreads();

#pragma unroll
                for (int kk = 0; kk < 2; kk++) {
                    const int sbase = kk * 4 + (lane >> 4);
                    half8 af[4], bf[2];
#pragma unroll
                    for (int mi = 0; mi < 4; mi++) {
                        int r = wm * 64 + mi * 16 + (lane & 15);
                        af[mi] = *(const half8*)&smA[r][(sbase ^ (r & 7)) * 8];
                    }
#pragma unroll
                    for (int ni = 0; ni < 2; ni++) {
                        int rb = wn * 32 + ni * 16 + (lane & 15);
                        bf[ni] = *(const half8*)&smB[kt & 1][rb][(sbase ^ (rb & 7)) * 8];
                    }
#pragma unroll
                    for (int mi = 0; mi < 4; mi++)
#pragma unroll
                        for (int ni = 0; ni < 2; ni++)
                            acc[mi][ni] = __builtin_amdgcn_mfma_f32_16x16x32_f16(
                                af[mi], bf[ni], acc[mi][ni], 0, 0, 0);
                }
                __syncthreads();
            }
#undef STAGE_B

            // epilogue: per-row top-2 + sumexp; uncached partial stores
            const int colbase = v0 + wn * 32 + (lane & 15);
            const float bias0 = blin[colbase];
            const float bias1 = blin[colbase + 16];
            const int cidx = blk * 4 + wn;

#pragma unroll
            for (int mi = 0; mi < 4; mi++) {
#pragma unroll
                for (int reg = 0; reg < 4; reg++) {
                    const int bRow = wm * 64 + mi * 16 + (lane >> 4) * 4 + reg;
                    const float va = acc[mi][0][reg] + bias0;
                    const float vc = acc[mi][1][reg] + bias1;
                    float v1, v2; int j1, j2;
                    if (va >= vc) { v1 = va; j1 = colbase;      v2 = vc; j2 = colbase + 16; }
                    else          { v1 = vc; j1 = colbase + 16; v2 = va; j2 = colbase; }
#pragma unroll
                    for (int off = 1; off < 16; off <<= 1) {
                        float o1 = __shfl_xor(v1, off), o2 = __shfl_xor(v2, off);
                        int   k1 = __shfl_xor(j1, off), k2 = __shfl_xor(j2, off);
                        float n1, n2; int m1, m2;
                        bool ob = (o1 > v1) || (o1 == v1 && k1 < j1);
                        if (ob) {
                            n1 = o1; m1 = k1;
                            bool t2 = (v1 > o2) || (v1 == o2 && j1 < k2);
                            if (t2) { n2 = v1; m2 = j1; } else { n2 = o2; m2 = k2; }
                        } else {
                            n1 = v1; m1 = j1;
                            bool t2 = (o1 > v2) || (o1 == v2 && k1 < j2);
                            if (t2) { n2 = o1; m2 = k1; } else { n2 = v2; m2 = j2; }
                        }
                        v1 = n1; j1 = m1; v2 = n2; j2 = m2;
                    }
                    float s = __expf(va - v1) + __expf(vc - v1);
#pragma unroll
                    for (int off = 1; off < 16; off <<= 1) s += __shfl_xor(s, off);
                    if ((lane & 15) == 0) {
                        const int idx = bRow * NVBW + cidx;
                        AGST(pm1 + idx, v1);  AGST(pi1 + idx, j1);
                        AGST(pm2 + idx, v2);  AGST(pi2 + idx, j2);
                        AGST(ps + idx, s);
                    }
                }
            }
        }
        ++sno; gsync(cnt, sno * 256u);

        // ================= emit + RNN phase (blocks 0..127) =============
        if (blk < NB) {
            constexpr float DELTA = 0.01f;
            constexpr int   MAXC  = 32;
            const int b = blk;
            const float* hid_in = (t == 0) ? z : hid;

            // zero this (t,b) one-hot row (d_out is poisoned each replay)
            {
                const float4 zz = {0.f, 0.f, 0.f, 0.f};
                float4* orow = (float4*)(out + (size_t)t * NB * NV + (size_t)b * NV);
                for (int i = tid; i < NV / 4; i += 512) orow[i] = zz;
            }
            hs[tid] = hid_in[(size_t)b * NH + tid];
            if (tid == 0) ncand = 0;
            // drain zero-stores before any thread can write the one-hot 1.0
            asm volatile("s_waitcnt vmcnt(0)" ::: "memory");
            __syncthreads();

            // phase 1: global max of pm1 (uncached loads)
            float m_ = -1e30f;
            for (int c = tid; c < NVBW; c += 512)
                m_ = fmaxf(m_, AGLD(pm1 + b * NVBW + c));
#pragma unroll
            for (int off = 1; off < 64; off <<= 1) m_ = fmaxf(m_, __shfl_xor(m_, off));
            if (lane == 0) red8[w] = m_;
            __syncthreads();
            const float gmax = fmaxf(fmaxf(fmaxf(red8[0], red8[1]), fmaxf(red8[2], red8[3])),
                                     fmaxf(fmaxf(red8[4], red8[5]), fmaxf(red8[6], red8[7])));
            __syncthreads();

            // phase 2: softmax denominator + candidate collection
            float s = 0.f;
            for (int c = tid; c < NVBW; c += 512) {
                float p1 = AGLD(pm1 + b * NVBW + c);
                s += AGLD(ps + b * NVBW + c) * __expf(p1 - gmax);
                if (p1 >= gmax - DELTA) {
                    int pos = atomicAdd(&ncand, 1);
                    if (pos < MAXC) cand[pos] = AGLD(pi1 + b * NVBW + c);
                }
                float p2 = AGLD(pm2 + b * NVBW + c);
                if (p2 >= gmax - DELTA) {
                    int pos = atomicAdd(&ncand, 1);
                    if (pos < MAXC) cand[pos] = AGLD(pi2 + b * NVBW + c);
                }
            }
#pragma unroll
            for (int off = 1; off < 64; off <<= 1) s += __shfl_xor(s, off);
            if (lane == 0) red8[w] = s;
            __syncthreads();
            const float tot = ((red8[0] + red8[1]) + (red8[2] + red8[3]))
                            + ((red8[4] + red8[5]) + (red8[6] + red8[7]));
            const int nc = min(ncand, MAXC);

            // phase 3: exact fp32 rescore of candidates (one wave each)
            for (int ci = w; ci < nc; ci += 8) {
                int tok = cand[ci];
                float4 h0 = ((const float4*)hs)[lane * 2];
                float4 h1 = ((const float4*)hs)[lane * 2 + 1];
                const float4* wv = (const float4*)(Wlin + (size_t)tok * NH);
                float4 w0 = wv[lane * 2], w1 = wv[lane * 2 + 1];
                float d = h0.x * w0.x + h0.y * w0.y + h0.z * w0.z + h0.w * w0.w
                        + h1.x * w1.x + h1.y * w1.y + h1.z * w1.z + h1.w * w1.w;
#pragma unroll
                for (int off = 1; off < 64; off <<= 1) d += __shfl_xor(d, off);
                if (lane == 0) cval[ci] = d + blin[tok];
            }
            __syncthreads();

            // phase 4: argmax among candidates; state update; one-hot write
            if (tid == 0) {
                float bv = cval[0]; int bi = cand[0];
                for (int ci = 1; ci < nc; ci++)
                    if (cval[ci] > bv || (cval[ci] == bv && cand[ci] < bi)) { bv = cval[ci]; bi = cand[ci]; }
                float lp = (bv - gmax) - logf(tot);
                float lpv, mk;
                if (t == 0) { lpv = lp; mk = (bi == 0) ? 0.f : 1.f; }
                else {
                    lpv = lps[b]; mk = maskp[b];
                    lpv += mk * lp;
                    mk *= (bi == 0) ? 0.f : 1.f;
                }
                lps[b] = lpv; maskp[b] = mk;
                out[(size_t)t * NB * NV + (size_t)b * NV + bi] = 1.0f;
                if (t == NT - 1) out[(size_t)NT * NB * NV + b] = lpv;
                besti = bi;
            }
            __syncthreads();
            const int gi = besti;

            if (t < NT - 1) {
                // phase 5: embedding gather
                if (tid < NE) es[tid] = Wemb[(size_t)tid * NV + gi] + bemb[tid];
                __syncthreads();

                // phase 6: Elman cell (512 threads, 1 h each)
                const int h = tid;
                float acc = bih[h] + bhh[h];
                const float4* wi = (const float4*)(Wih + (size_t)h * NE);
#pragma unroll 4
                for (int e4 = 0; e4 < NE / 4; e4++) {
                    float4 ww = wi[e4];
                    acc += ww.x * es[e4 * 4] + ww.y * es[e4 * 4 + 1]
                         + ww.z * es[e4 * 4 + 2] + ww.w * es[e4 * 4 + 3];
                }
                const float4* wh = (const float4*)(Whh + (size_t)h * NH);
#pragma unroll 4
                for (int k4 = 0; k4 < NH / 4; k4++) {
                    float4 ww = wh[k4];
                    acc += ww.x * hs[k4 * 4] + ww.y * hs[k4 * 4 + 1]
                         + ww.z * hs[k4 * 4 + 2] + ww.w * hs[k4 * 4 + 3];
                }
                float v = tanhf(acc);
                hid[(size_t)b * NH + h] = v;       // block-local, cached
                hsout[h] = (_Float16)v;
                __syncthreads();
                if (tid < 256) {                    // pack + uncached store
                    union { _Float16 h2[2]; unsigned u; } p;
                    p.h2[0] = hsout[2 * tid]; p.h2[1] = hsout[2 * tid + 1];
                    AGST((unsigned*)hidh64 + b * 256 + tid, p.u);
                }
            }
        }
        ++sno; gsync(cnt, sno * 256u);
    }
}

// ---------------------------------------------------------------------------
extern "C" void kernel_launch(void* const* d_in, const int* in_sizes, int n_in,
                              void* d_out, int out_size, void* d_ws, size_t ws_size,
                              hipStream_t stream) {
    const float* z    = (const float*)d_in[0];
    const float* Wemb = (const float*)d_in[1];
    const float* bemb = (const float*)d_in[2];
    const float* Wih  = (const float*)d_in[3];
    const float* bih  = (const float*)d_in[4];
    const float* Whh  = (const float*)d_in[5];
    const float* bhh  = (const float*)d_in[6];
    const float* Wlin = (const float*)d_in[7];
    const float* blin = (const float*)d_in[8];
    float* out = (float*)d_out;

    char* ws = (char*)d_ws;
    _Float16* Wh  = (_Float16*)(ws);                                  // 32,768,000 B
    unsigned long long* hidh64 = (unsigned long long*)(ws + 32768000);// 131,072 B
    float*    hid   = (float*)(ws + 32899072);                        // 262,144 B
    float*    pm1   = (float*)(ws + 33161216);                        // 512,000 B
    int*      pi1   = (int*)  (ws + 33673216);
    float*    pm2   = (float*)(ws + 34185216);
    int*      pi2   = (int*)  (ws + 34697216);
    float*    ps    = (float*)(ws + 35209216);
    float*    lps   = (float*)(ws + 35721216);                        // 512 B
    float*    maskp = (float*)(ws + 35721728);                        // 512 B
    unsigned* cnt   = (unsigned*)(ws + 35722240);

    init_kernel<<<1, 1, 0, stream>>>(cnt);

    void* args[] = {
        (void*)&z, (void*)&Wemb, (void*)&bemb, (void*)&Wih, (void*)&bih,
        (void*)&Whh, (void*)&bhh, (void*)&Wlin, (void*)&blin, (void*)&out,
        (void*)&Wh, (void*)&hidh64, (void*)&hid,
        (void*)&pm1, (void*)&pi1, (void*)&pm2, (void*)&pi2, (void*)&ps,
        (void*)&lps, (void*)&maskp, (void*)&cnt
    };
    hipLaunchCooperativeKernel((void*)speaker_kernel, dim3(256), dim3(512),
                               args, 0, stream);
}

// Round 8
// 3179.260 us; speedup vs baseline: 2.4996x; 1.1341x over previous
//
#include <hip/hip_runtime.h>
#include <math.h>

// Problem constants
constexpr int NB = 128;    // batch
constexpr int NH = 512;    // hidden
constexpr int NE = 256;    // embed
constexpr int NV = 32000;  // vocab
constexpr int NT = 32;     // steps
constexpr int NVBW = 1000; // 250 v-blocks * 4 wave-columns (32 vocab each)

typedef _Float16 half8 __attribute__((ext_vector_type(8)));
typedef float    f32x4 __attribute__((ext_vector_type(4)));
typedef unsigned long long u64;

#define AGLD(p)    __hip_atomic_load((p), __ATOMIC_RELAXED, __HIP_MEMORY_SCOPE_AGENT)
#define AGST(p, v) __hip_atomic_store((p), (v), __ATOMIC_RELAXED, __HIP_MEMORY_SCOPE_AGENT)

__global__ void init_kernel(unsigned* cnt) { *cnt = 0u; }

// Fence-free grid barrier (validated r6). Data handoff rules:
//  - producers store UNCACHED (AGST) and are drained by vmcnt(0) before arrival
//  - consumers either AGLD, or plain cached loads of addresses written at most
//    once per launch (first touch misses L2 -> fetches from MALL = coherent;
//    cross-replay staleness killed by kernel-launch acquire-invalidate).
__device__ __forceinline__ void gsync(unsigned* cnt, unsigned target) {
    asm volatile("s_waitcnt vmcnt(0) lgkmcnt(0)" ::: "memory");
    __syncthreads();
    if (threadIdx.x == 0) {
        __hip_atomic_fetch_add(cnt, 1u, __ATOMIC_RELAXED, __HIP_MEMORY_SCOPE_AGENT);
        while (AGLD(cnt) < target) __builtin_amdgcn_s_sleep(4);
    }
    __syncthreads();
    asm volatile("" ::: "memory");
}

// ---------------------------------------------------------------------------
// Cooperative mega-kernel: 256 blocks x 512 threads (1/CU, persistent).
// ---------------------------------------------------------------------------
__global__ __launch_bounds__(512, 1)
void speaker_kernel(const float* __restrict__ z,    const float* __restrict__ Wemb,
                    const float* __restrict__ bemb, const float* __restrict__ Wih,
                    const float* __restrict__ bih,  const float* __restrict__ Whh,
                    const float* __restrict__ bhh,  const float* __restrict__ Wlin,
                    const float* __restrict__ blin, float* __restrict__ out,
                    _Float16* __restrict__ Wh,      _Float16* __restrict__ hidh,
                    float* __restrict__ hid,
                    float* __restrict__ pm1, int* __restrict__ pi1,
                    float* __restrict__ pm2, int* __restrict__ pi2,
                    float* __restrict__ ps,  float* __restrict__ lps,
                    float* __restrict__ maskp, unsigned* __restrict__ cnt)
{
    // LDS arena (phases overlap; separated by gsync's __syncthreads)
    __shared__ __align__(16) char arena[75776];
    _Float16* smp  = (_Float16*)arena;              // [2][2][128][64] f16, 64 KiB
    float*    SV1  = (float*)(arena + 65536);       // [8][64]
    float*    SV2  = (float*)(arena + 67584);
    float*    SSe  = (float*)(arena + 69632);
    int*      SJ1  = (int*)  (arena + 71680);
    int*      SJ2  = (int*)  (arena + 73728);
    // emit-phase views (reuse low arena)
    float*    hsf  = (float*)arena;                 // [512]
    float*    esf  = (float*)(arena + 2048);        // [256]
    _Float16* hof  = (_Float16*)(arena + 3072);     // [512]
    float*    red8 = (float*)(arena + 4096);        // [8]
    int*      candp= (int*)  (arena + 4128);        // [32]
    float*    cvalp= (float*)(arena + 4256);        // [32]
    int*      ncp  = (int*)  (arena + 4384);
    int*      bip  = (int*)  (arena + 4388);

    const int blk  = blockIdx.x;
    const int tid  = threadIdx.x;
    const int w    = tid >> 6;
    const int lane = tid & 63;
    const int gtid = blk * 512 + tid;
    constexpr int GT = 256 * 512;
    unsigned sno = 0;

    u64* Wh64   = (u64*)Wh;
    u64* hidh64 = (u64*)hidh;

    // ---- P0: convert Wlin->Wh, z->hidh[0]; zero out[0] rows + lps row ---
    for (int i = gtid; i < NV * NH / 4; i += GT) {
        float4 a = ((const float4*)Wlin)[i];
        union { _Float16 h[4]; u64 u; } p;
        p.h[0] = (_Float16)a.x; p.h[1] = (_Float16)a.y;
        p.h[2] = (_Float16)a.z; p.h[3] = (_Float16)a.w;
        AGST(Wh64 + i, p.u);
    }
    for (int i = gtid; i < NB * NH / 4; i += GT) {
        float4 a = ((const float4*)z)[i];
        union { _Float16 h[4]; u64 u; } p;
        p.h[0] = (_Float16)a.x; p.h[1] = (_Float16)a.y;
        p.h[2] = (_Float16)a.z; p.h[3] = (_Float16)a.w;
        AGST(hidh64 + i, p.u);
    }
    for (int i = gtid; i < NB * NV / 2; i += GT) AGST((u64*)out + i, 0ull);
    if (gtid < 64) AGST((u64*)(out + (size_t)NT * NB * NV) + gtid, 0ull);
    ++sno; gsync(cnt, sno * 256u);

    const int eb = (blk & 7) * 16 + (blk >> 3);   // XCD-affine batch row (blk<128)

    for (int t = 0; t < NT; t++) {
        // ================= logits phase (blocks 0..249) =================
        if (blk < 250) {
            const int wm = w >> 2;
            const int wn = w & 3;
            const int v0 = blk * 128;
            const _Float16* Abase = hidh + (size_t)t * NB * NH;  // cached (write-once)

            const _Float16* gp[4];
            unsigned ldsoff[4];
#pragma unroll
            for (int c = 0; c < 4; c++) {
                int slot = w * 256 + c * 64 + lane;
                int mat  = slot >> 10;
                int r    = (slot >> 3) & 127;
                int sp   = slot & 7;
                int s    = sp ^ (r & 7);
                const _Float16* base = mat ? (Wh + (size_t)(v0 + r) * NH)
                                           : (Abase + (size_t)r * NH);
                gp[c] = base + s * 8;
                ldsoff[c] = (unsigned)(w * 256 + c * 64) * 16;  // wave-uniform
            }

#define STAGE(db, k0)                                                          \
    do {                                                                       \
        _Pragma("unroll")                                                      \
        for (int c = 0; c < 4; c++) {                                          \
            __builtin_amdgcn_global_load_lds(                                  \
                (const __attribute__((address_space(1))) unsigned*)(gp[c] + (k0)), \
                (__attribute__((address_space(3))) unsigned*)(arena + (db) * 32768 + ldsoff[c]), \
                16, 0, 0);                                                     \
        }                                                                      \
    } while (0)

            f32x4 acc[4][2];
#pragma unroll
            for (int mi = 0; mi < 4; mi++)
#pragma unroll
                for (int ni = 0; ni < 2; ni++) acc[mi][ni] = {0.f, 0.f, 0.f, 0.f};

            STAGE(0, 0);
            asm volatile("s_waitcnt vmcnt(0)" ::: "memory");
            __builtin_amdgcn_sched_barrier(0);
            __builtin_amdgcn_s_barrier();

            int db = 0;
#pragma unroll 1
            for (int kt = 0; kt < 8; kt++) {
                if (kt < 7) STAGE(db ^ 1, (kt + 1) * 64);
#pragma unroll
                for (int kk = 0; kk < 2; kk++) {
                    const int sbase = kk * 4 + (lane >> 4);
                    half8 af[4], bf[2];
#pragma unroll
                    for (int mi = 0; mi < 4; mi++) {
                        int r = wm * 64 + mi * 16 + (lane & 15);
                        af[mi] = *(const half8*)&smp[((db * 2 + 0) * 128 + r) * 64 + ((sbase ^ (r & 7)) * 8)];
                    }
#pragma unroll
                    for (int ni = 0; ni < 2; ni++) {
                        int rb = wn * 32 + ni * 16 + (lane & 15);
                        bf[ni] = *(const half8*)&smp[((db * 2 + 1) * 128 + rb) * 64 + ((sbase ^ (rb & 7)) * 8)];
                    }
#pragma unroll
                    for (int mi = 0; mi < 4; mi++)
#pragma unroll
                        for (int ni = 0; ni < 2; ni++)
                            acc[mi][ni] = __builtin_amdgcn_mfma_f32_16x16x32_f16(
                                af[mi], bf[ni], acc[mi][ni], 0, 0, 0);
                }
                asm volatile("s_waitcnt vmcnt(0)" ::: "memory");
                __builtin_amdgcn_sched_barrier(0);
                __builtin_amdgcn_s_barrier();
                db ^= 1;
            }
#undef STAGE

            // epilogue: per-row top-2 + sumexp -> LDS transpose -> coalesced
            // uncached stores into step-indexed [t][c][b] partial arrays
            const int colbase = v0 + wn * 32 + (lane & 15);
            const float bias0 = blin[colbase];
            const float bias1 = blin[colbase + 16];
            const int cidx = blk * 4 + wn;

#pragma unroll
            for (int mi = 0; mi < 4; mi++) {
#pragma unroll
                for (int reg = 0; reg < 4; reg++) {
                    const float va = acc[mi][0][reg] + bias0;
                    const float vc = acc[mi][1][reg] + bias1;
                    float v1, v2; int j1, j2;
                    if (va >= vc) { v1 = va; j1 = colbase;      v2 = vc; j2 = colbase + 16; }
                    else          { v1 = vc; j1 = colbase + 16; v2 = va; j2 = colbase; }
#pragma unroll
                    for (int off = 1; off < 16; off <<= 1) {
                        float o1 = __shfl_xor(v1, off), o2 = __shfl_xor(v2, off);
                        int   k1 = __shfl_xor(j1, off), k2 = __shfl_xor(j2, off);
                        float n1, n2; int m1, m2;
                        bool ob = (o1 > v1) || (o1 == v1 && k1 < j1);
                        if (ob) {
                            n1 = o1; m1 = k1;
                            bool t2 = (v1 > o2) || (v1 == o2 && j1 < k2);
                            if (t2) { n2 = v1; m2 = j1; } else { n2 = o2; m2 = k2; }
                        } else {
                            n1 = v1; m1 = j1;
                            bool t2 = (o1 > v2) || (o1 == v2 && k1 < j2);
                            if (t2) { n2 = o1; m2 = k1; } else { n2 = v2; m2 = j2; }
                        }
                        v1 = n1; j1 = m1; v2 = n2; j2 = m2;
                    }
                    float s = __expf(va - v1) + __expf(vc - v1);
#pragma unroll
                    for (int off = 1; off < 16; off <<= 1) s += __shfl_xor(s, off);
                    if ((lane & 15) == 0) {
                        const int idx = mi * 16 + (lane >> 4) * 4 + reg;  // 0..63
                        SV1[w * 64 + idx] = v1;  SJ1[w * 64 + idx] = j1;
                        SV2[w * 64 + idx] = v2;  SJ2[w * 64 + idx] = j2;
                        SSe[w * 64 + idx] = s;
                    }
                }
            }
            // coalesced write: lane i -> bRow = wm*64 + i (256B contiguous)
            {
                const size_t gOff = ((size_t)t * NVBW + cidx) * NB + wm * 64 + lane;
                AGST(pm1 + gOff, SV1[w * 64 + lane]);
                AGST(pi1 + gOff, SJ1[w * 64 + lane]);
                AGST(pm2 + gOff, SV2[w * 64 + lane]);
                AGST(pi2 + gOff, SJ2[w * 64 + lane]);
                AGST(ps  + gOff, SSe[w * 64 + lane]);
            }
        }
        ++sno; gsync(cnt, sno * 256u);

        // ======== emit + RNN (blocks 0..127) | zero next rows (128..255) ====
        if (blk < NB) {
            constexpr float DELTA = 0.01f;
            constexpr int   MAXC  = 32;
            const int b = eb;
            const float* hid_in = (t == 0) ? z : hid;
            const float* pm1t = pm1 + (size_t)t * NVBW * NB;
            const float* pm2t = pm2 + (size_t)t * NVBW * NB;
            const float* pst  = ps  + (size_t)t * NVBW * NB;
            const int*   pi1t = pi1 + (size_t)t * NVBW * NB;
            const int*   pi2t = pi2 + (size_t)t * NVBW * NB;

            hsf[tid] = hid_in[(size_t)b * NH + tid];
            if (tid == 0) *ncp = 0;
            __syncthreads();

            // phase 1: global max (cached reads; write-once addresses)
            float m_ = -1e30f;
            for (int c = tid; c < NVBW; c += 512) m_ = fmaxf(m_, pm1t[c * NB + b]);
#pragma unroll
            for (int off = 1; off < 64; off <<= 1) m_ = fmaxf(m_, __shfl_xor(m_, off));
            if (lane == 0) red8[w] = m_;
            __syncthreads();
            const float gmax = fmaxf(fmaxf(fmaxf(red8[0], red8[1]), fmaxf(red8[2], red8[3])),
                                     fmaxf(fmaxf(red8[4], red8[5]), fmaxf(red8[6], red8[7])));
            __syncthreads();

            // phase 2: softmax denominator + candidate collection
            float s = 0.f;
            for (int c = tid; c < NVBW; c += 512) {
                float p1 = pm1t[c * NB + b];
                s += pst[c * NB + b] * __expf(p1 - gmax);
                if (p1 >= gmax - DELTA) {
                    int pos = atomicAdd(ncp, 1);
                    if (pos < MAXC) candp[pos] = pi1t[c * NB + b];
                }
                float p2 = pm2t[c * NB + b];
                if (p2 >= gmax - DELTA) {
                    int pos = atomicAdd(ncp, 1);
                    if (pos < MAXC) candp[pos] = pi2t[c * NB + b];
                }
            }
#pragma unroll
            for (int off = 1; off < 64; off <<= 1) s += __shfl_xor(s, off);
            if (lane == 0) red8[w] = s;
            __syncthreads();
            const float tot = ((red8[0] + red8[1]) + (red8[2] + red8[3]))
                            + ((red8[4] + red8[5]) + (red8[6] + red8[7]));
            const int nc = min(*ncp, MAXC);

            // phase 3: exact fp32 rescore of candidates (one wave each)
            for (int ci = w; ci < nc; ci += 8) {
                int tok = candp[ci];
                float4 h0 = ((const float4*)hsf)[lane * 2];
                float4 h1 = ((const float4*)hsf)[lane * 2 + 1];
                const float4* wv = (const float4*)(Wlin + (size_t)tok * NH);
                float4 w0 = wv[lane * 2], w1 = wv[lane * 2 + 1];
                float d = h0.x * w0.x + h0.y * w0.y + h0.z * w0.z + h0.w * w0.w
                        + h1.x * w1.x + h1.y * w1.y + h1.z * w1.z + h1.w * w1.w;
#pragma unroll
                for (int off = 1; off < 64; off <<= 1) d += __shfl_xor(d, off);
                if (lane == 0) cvalp[ci] = d + blin[tok];
            }
            __syncthreads();

            // phase 4: argmax among candidates; state; one-hot (uncached)
            if (tid == 0) {
                float bv = cvalp[0]; int bi = candp[0];
                for (int ci = 1; ci < nc; ci++)
                    if (cvalp[ci] > bv || (cvalp[ci] == bv && candp[ci] < bi)) { bv = cvalp[ci]; bi = candp[ci]; }
                float lp = (bv - gmax) - logf(tot);
                float lpv, mk;
                if (t == 0) { lpv = lp; mk = (bi == 0) ? 0.f : 1.f; }
                else {
                    lpv = lps[b]; mk = maskp[b];
                    lpv += mk * lp;
                    mk *= (bi == 0) ? 0.f : 1.f;
                }
                lps[b] = lpv; maskp[b] = mk;   // block-private state (cached)
                AGST(out + (size_t)t * NB * NV + (size_t)b * NV + bi, 1.0f);
                if (t == NT - 1) AGST(out + (size_t)NT * NB * NV + b, lpv);
                *bip = bi;
            }
            __syncthreads();
            const int gi = *bip;

            if (t < NT - 1) {
                // phase 5: embedding gather
                if (tid < NE) esf[tid] = Wemb[(size_t)tid * NV + gi] + bemb[tid];
                __syncthreads();

                // phase 6: Elman cell (512 threads, 1 h each)
                const int h = tid;
                float acc = bih[h] + bhh[h];
                const float4* wi = (const float4*)(Wih + (size_t)h * NE);
#pragma unroll 4
                for (int e4 = 0; e4 < NE / 4; e4++) {
                    float4 ww = wi[e4];
                    acc += ww.x * esf[e4 * 4] + ww.y * esf[e4 * 4 + 1]
                         + ww.z * esf[e4 * 4 + 2] + ww.w * esf[e4 * 4 + 3];
                }
                const float4* wh = (const float4*)(Whh + (size_t)h * NH);
#pragma unroll 4
                for (int k4 = 0; k4 < NH / 4; k4++) {
                    float4 ww = wh[k4];
                    acc += ww.x * hsf[k4 * 4] + ww.y * hsf[k4 * 4 + 1]
                         + ww.z * hsf[k4 * 4 + 2] + ww.w * hsf[k4 * 4 + 3];
                }
                float v = tanhf(acc);
                hid[(size_t)b * NH + h] = v;    // block-private (cached)
                hof[h] = (_Float16)v;
                __syncthreads();
                if (tid < 256) {                // uncached f16 state handoff
                    union { _Float16 h2[2]; unsigned u; } p;
                    p.h2[0] = hof[2 * tid]; p.h2[1] = hof[2 * tid + 1];
                    AGST((unsigned*)(hidh + (size_t)(t + 1) * NB * NH + (size_t)b * NH) + tid, p.u);
                }
            }
        } else if (t < NT - 1) {
            // blocks 128..255: zero step-(t+1) one-hot rows (uncached, no WB hazard)
            u64* dst = (u64*)(out + (size_t)(t + 1) * NB * NV);
            for (int i = (blk - 128) * 512 + tid; i < NB * NV / 2; i += 128 * 512)
                AGST(dst + i, 0ull);
        }
        ++sno; gsync(cnt, sno * 256u);
    }
}

// ---------------------------------------------------------------------------
extern "C" void kernel_launch(void* const* d_in, const int* in_sizes, int n_in,
                              void* d_out, int out_size, void* d_ws, size_t ws_size,
                              hipStream_t stream) {
    const float* z    = (const float*)d_in[0];
    const float* Wemb = (const float*)d_in[1];
    const float* bemb = (const float*)d_in[2];
    const float* Wih  = (const float*)d_in[3];
    const float* bih  = (const float*)d_in[4];
    const float* Whh  = (const float*)d_in[5];
    const float* bhh  = (const float*)d_in[6];
    const float* Wlin = (const float*)d_in[7];
    const float* blin = (const float*)d_in[8];
    float* out = (float*)d_out;

    char* ws = (char*)d_ws;
    _Float16* Wh    = (_Float16*)(ws);                  // 32,768,000 B
    _Float16* hidh  = (_Float16*)(ws + 32768000);       // [NT][NB][NH] f16: 4,194,304 B
    float*    hid   = (float*)   (ws + 36962304);       // 262,144 B
    float*    pm1   = (float*)   (ws + 37224448);       // [NT][1000][128] f32: 16,384,000 B
    int*      pi1   = (int*)     (ws + 53608448);
    float*    pm2   = (float*)   (ws + 69992448);
    int*      pi2   = (int*)     (ws + 86376448);
    float*    ps    = (float*)   (ws + 102760448);
    float*    lps   = (float*)   (ws + 119144448);      // 512 B
    float*    maskp = (float*)   (ws + 119144960);      // 512 B
    unsigned* cnt   = (unsigned*)(ws + 119145472);

    init_kernel<<<1, 1, 0, stream>>>(cnt);

    void* args[] = {
        (void*)&z, (void*)&Wemb, (void*)&bemb, (void*)&Wih, (void*)&bih,
        (void*)&Whh, (void*)&bhh, (void*)&Wlin, (void*)&blin, (void*)&out,
        (void*)&Wh, (void*)&hidh, (void*)&hid,
        (void*)&pm1, (void*)&pi1, (void*)&pm2, (void*)&pi2, (void*)&ps,
        (void*)&lps, (void*)&maskp, (void*)&cnt
    };
    hipLaunchCooperativeKernel((void*)speaker_kernel, dim3(256), dim3(512),
                               args, 0, stream);
}